// Round 4
// baseline (1312.284 us; speedup 1.0000x reference)
//
#include <hip/hip_runtime.h>
#include <cstdint>

typedef __bf16 bf16;
typedef __attribute__((ext_vector_type(4))) __bf16 bf16x4;
typedef __attribute__((ext_vector_type(8))) __bf16 bf16x8;
typedef __attribute__((ext_vector_type(4))) float f32x4;

#define DEVI __device__ __forceinline__

#define BATCH 2
#define SEQ 2048
#define HID 4096
#define NH 32
#define NKVH 8
#define HD 128
#define QKVN 6144
#define MROWS 4096
#define ATT_SCALE 0.08838834764831845f

DEVI void gload_lds16(const bf16* g, bf16* l) {
  __builtin_amdgcn_global_load_lds(
      (__attribute__((address_space(1))) void*)(g),
      (__attribute__((address_space(3))) void*)(l), 16, 0, 0);
}

// ---------------- elementwise f32 -> bf16 ----------------
__global__ void h2b_kernel(const float* __restrict__ in, bf16* __restrict__ out) {
  long i = ((long)blockIdx.x * 256 + threadIdx.x) * 4;
  float4 v = *(const float4*)(in + i);
  bf16x4 o;
  o[0] = (bf16)v.x; o[1] = (bf16)v.y; o[2] = (bf16)v.z; o[3] = (bf16)v.w;
  *(bf16x4*)(out + i) = o;
}

// ---------------- transpose-convert weight: in (K,N) f32 -> out (N,K) bf16 ----------------
__global__ void wtrans_kernel(const float* __restrict__ in, bf16* __restrict__ out,
                              int K, int N) {
  __shared__ float t[32][33];
  int n0 = blockIdx.x * 32, k0 = blockIdx.y * 32;
  int tx = threadIdx.x, ty = threadIdx.y; // (32,8)
#pragma unroll
  for (int r = 0; r < 4; ++r) {
    int k = ty + r * 8;
    t[k][tx] = in[(long)(k0 + k) * N + n0 + tx];
  }
  __syncthreads();
#pragma unroll
  for (int r = 0; r < 4; ++r) {
    int n = ty + r * 8;
    out[(long)(n0 + n) * K + k0 + tx] = (bf16)t[tx][n];
  }
}

// ---------------- RoPE in-place on q,k columns of qkv ----------------
__global__ void rope_kernel(bf16* __restrict__ qkv, const int* __restrict__ pos) {
  long idx = (long)blockIdx.x * 256 + threadIdx.x;
  if (idx >= (long)MROWS * 40 * 64) return;
  int d = idx & 63;
  long t = idx >> 6;
  int hh = (int)(t % 40);
  int row = (int)(t / 40);
  int colb = hh < NH ? hh * HD : NH * HD + (hh - NH) * HD;
  float p = (float)pos[row];
  float inv_freq = exp2f((float)d * -0.2076205059304601f);
  float ang = p * inv_freq;
  float sn = sinf(ang), cs = cosf(ang);
  bf16* base = qkv + (long)row * QKVN + colb + d;
  float x1 = (float)base[0], x2 = (float)base[64];
  base[0] = (bf16)(x1 * cs - x2 * sn);
  base[64] = (bf16)(x2 * cs + x1 * sn);
}

// ---------------- transpose V: qkv v-cols -> vt (b,kvh,D,S) ----------------
__global__ void vtrans_kernel(const bf16* __restrict__ qkv, bf16* __restrict__ vt) {
  __shared__ bf16 t[32][33];
  int s0 = blockIdx.x * 32, d0 = blockIdx.y * 32, bk = blockIdx.z;
  int b = bk >> 3, kvh = bk & 7;
  int tx = threadIdx.x, ty = threadIdx.y; // (32,8)
#pragma unroll
  for (int r = 0; r < 4; ++r) {
    int s = ty + r * 8;
    t[s][tx] = qkv[(long)(b * SEQ + s0 + s) * QKVN + 5120 + kvh * HD + d0 + tx];
  }
  __syncthreads();
#pragma unroll
  for (int r = 0; r < 4; ++r) {
    int d = ty + r * 8;
    vt[((long)bk * HD + d0 + d) * SEQ + s0 + tx] = t[tx][d];
  }
}

// ---------------- pipelined GEMM: C(M,N) = A(M,K) x BT(N,K)^T ----------------
// 256x128 tile, BK=64, 8 waves (4M x 2N), wave-tile 64x64. Ring-3 LDS.
template <typename OutT>
__global__ __launch_bounds__(512, 2)
void gemm256(const bf16* __restrict__ A, const bf16* __restrict__ BT,
             OutT* __restrict__ C, int M, int N, int K) {
  extern __shared__ __align__(16) bf16 lds[];
  const int tid = threadIdx.x;
  const int lane = tid & 63, wave = tid >> 6;
  const int wm = wave >> 1, wn = wave & 1;
  const int l16 = lane & 15, lhi = lane >> 4;
  const int nwg = gridDim.x * gridDim.y;
  const int bid = blockIdx.y * gridDim.x + blockIdx.x;
  const int cpx = nwg >> 3;
  const int swz = (bid & 7) * cpx + (bid >> 3);
  const int bx = swz % gridDim.x, by = swz / gridDim.x;
  const long bm0 = (long)by * 256, bn0 = (long)bx * 128;

  const int srow8 = lane >> 3;
  const int scol = (lane & 7) ^ srow8;

  const int NT = K >> 6;
  f32x4 acc[4][4] = {};

  auto stage = [&](int slot, int t) {
    const long k0 = (long)t << 6;
    bf16* dst = lds + slot * 24576;
#pragma unroll
    for (int i = 0; i < 4; ++i) {
      int r = (wave * 4 + i) * 8 + srow8;
      gload_lds16(A + (bm0 + r) * K + k0 + scol * 8,
                  dst + (wave * 4 + i) * 512 + lane * 8);
    }
#pragma unroll
    for (int i = 0; i < 2; ++i) {
      int r = (wave * 2 + i) * 8 + srow8;
      gload_lds16(BT + (bn0 + r) * K + k0 + scol * 8,
                  dst + 16384 + (wave * 2 + i) * 512 + lane * 8);
    }
  };

  stage(0, 0);
  stage(1, 1);

  for (int t = 0; t < NT; ++t) {
    asm volatile("s_waitcnt vmcnt(6)" ::: "memory");
    __builtin_amdgcn_s_barrier();
    __builtin_amdgcn_sched_barrier(0);
    const int nxt = (t + 2 < NT) ? t + 2 : NT - 1;
    stage((t + 2) % 3, nxt);
    const bf16* As = lds + (t % 3) * 24576;
    const bf16* Bs = As + 16384;
#pragma unroll
    for (int kk = 0; kk < 2; ++kk) {
      bf16x8 af[4], bw[4];
#pragma unroll
      for (int i = 0; i < 4; ++i) {
        int ar = wm * 64 + i * 16 + l16;
        af[i] = *(const bf16x8*)(As + ar * 64 + (((kk * 4 + lhi) ^ (ar & 7))) * 8);
        int br = wn * 64 + i * 16 + l16;
        bw[i] = *(const bf16x8*)(Bs + br * 64 + (((kk * 4 + lhi) ^ (br & 7))) * 8);
      }
      __builtin_amdgcn_s_setprio(1);
#pragma unroll
      for (int i = 0; i < 4; ++i)
#pragma unroll
        for (int j = 0; j < 4; ++j)
          acc[i][j] = __builtin_amdgcn_mfma_f32_16x16x32_bf16(af[i], bw[j], acc[i][j], 0, 0, 0);
      __builtin_amdgcn_s_setprio(0);
    }
  }
  asm volatile("s_waitcnt vmcnt(0)" ::: "memory");
#pragma unroll
  for (int i = 0; i < 4; ++i)
#pragma unroll
    for (int r = 0; r < 4; ++r) {
      long grow = bm0 + wm * 64 + i * 16 + lhi * 4 + r;
#pragma unroll
      for (int j = 0; j < 4; ++j) {
        long gcol = bn0 + wn * 64 + j * 16 + l16;
        C[grow * N + gcol] = (OutT)acc[i][j][r];
      }
    }
}

// ---------------- flash attention, causal, GQA — barrier-free, LDS-free K/V ----------------
// grid (qt reversed, h, b), 256 threads = 4 waves x 16 q-rows.
// K and V MFMA fragments are loaded DIRECTLY from global (64B-aligned chunks,
// L1/L2-hot: each tile reused by 4 waves x 4 heads x 32 qt-blocks). No
// __syncthreads anywhere; only a tiny wave-private LDS P-buffer (same-wave
// write->read, lgkmcnt handled by compiler). Occupancy is VGPR-bound, not LDS-bound.
__global__ __launch_bounds__(256)
void attn_kernel(const bf16* __restrict__ qkv, const bf16* __restrict__ vt,
                 bf16* __restrict__ out) {
  __shared__ __align__(16) bf16 Ps[4][16 * 64];   // 8 KB, wave-private
  const int qt = (gridDim.x - 1) - blockIdx.x;    // longest blocks first
  const int h = blockIdx.y, b = blockIdx.z;
  const int kvh = h >> 2;
  const int tid = threadIdx.x, lane = tid & 63, wave = tid >> 6;
  const int l16 = lane & 15, lhi = lane >> 4;

  // Q fragments in registers
  bf16x8 qf[4];
  const bf16* qbase = qkv + (long)(b * SEQ + qt * 64 + wave * 16 + l16) * QKVN + h * HD + lhi * 8;
#pragma unroll
  for (int di = 0; di < 4; ++di) qf[di] = *(const bf16x8*)(qbase + di * 32);

  // per-lane K fragment base: K[kv0 + c*16 + l16][di*32 + lhi*8]
  const bf16* kbase = qkv + (long)(b * SEQ + l16) * QKVN + 4096 + kvh * HD + lhi * 8;
  // per-lane V fragment base: V^T[dj*16 + l16][kv0 + kh*32 + lhi*8]
  const bf16* vbase = vt + ((long)(b * NKVH + kvh) * HD + l16) * SEQ + lhi * 8;

  f32x4 oacc[8] = {};
  float m_run[4], l_run[4];
#pragma unroll
  for (int r = 0; r < 4; ++r) { m_run[r] = -1e30f; l_run[r] = 0.f; }
  const int qrow = qt * 64 + wave * 16 + lhi * 4;

  const int nsteps = qt + 1;
  for (int step = 0; step < nsteps; ++step) {
    const int kv0 = step * 64;
    // QK^T: K fragments straight from global
    f32x4 s[4];
    __builtin_amdgcn_s_setprio(1);
#pragma unroll
    for (int c = 0; c < 4; ++c) {
      s[c] = (f32x4){0.f, 0.f, 0.f, 0.f};
      const bf16* kc = kbase + (long)(kv0 + c * 16) * QKVN;
#pragma unroll
      for (int di = 0; di < 4; ++di) {
        bf16x8 kf = *(const bf16x8*)(kc + di * 32);
        s[c] = __builtin_amdgcn_mfma_f32_16x16x32_bf16(qf[di], kf, s[c], 0, 0, 0);
      }
    }
    __builtin_amdgcn_s_setprio(0);
    // scale + causal mask
#pragma unroll
    for (int c = 0; c < 4; ++c) {
      int col = kv0 + c * 16 + l16;
#pragma unroll
      for (int r = 0; r < 4; ++r) {
        float v = s[c][r] * ATT_SCALE;
        s[c][r] = (col <= qrow + r) ? v : -1e30f;
      }
    }
    // online softmax (row r across the 16 l16 lanes)
    float alpha[4];
#pragma unroll
    for (int r = 0; r < 4; ++r) {
      float m = fmaxf(fmaxf(s[0][r], s[1][r]), fmaxf(s[2][r], s[3][r]));
#pragma unroll
      for (int off = 1; off < 16; off <<= 1)
        m = fmaxf(m, __shfl_xor(m, off, 64));
      float mn = fmaxf(m_run[r], m);
      alpha[r] = __expf(m_run[r] - mn);
      m_run[r] = mn;
      float sm = 0.f;
#pragma unroll
      for (int c = 0; c < 4; ++c) {
        float p = __expf(s[c][r] - mn);
        s[c][r] = p;
        sm += p;
      }
#pragma unroll
      for (int off = 1; off < 16; off <<= 1)
        sm += __shfl_xor(sm, off, 64);
      l_run[r] = l_run[r] * alpha[r] + sm;
    }
    // P -> wave-private LDS (swizzled slots; no barrier needed, same-wave RAW)
#pragma unroll
    for (int c = 0; c < 4; ++c)
#pragma unroll
      for (int r = 0; r < 4; ++r) {
        int prow = lhi * 4 + r;
        int sl = (2 * c + (l16 >> 3)) ^ (prow & 7);
        Ps[wave][prow * 64 + sl * 8 + (l16 & 7)] = (bf16)s[c][r];
      }
    // rescale O
#pragma unroll
    for (int dj = 0; dj < 8; ++dj)
#pragma unroll
      for (int r = 0; r < 4; ++r) oacc[dj][r] *= alpha[r];
    // PV: V fragments straight from global
    __builtin_amdgcn_s_setprio(1);
#pragma unroll
    for (int kh = 0; kh < 2; ++kh) {
      bf16x8 pf = *(const bf16x8*)(&Ps[wave][l16 * 64 + (((kh * 4 + lhi) ^ (l16 & 7))) * 8]);
#pragma unroll
      for (int dj = 0; dj < 8; ++dj) {
        bf16x8 vf = *(const bf16x8*)(vbase + (long)(dj * 16) * SEQ + kv0 + kh * 32);
        oacc[dj] = __builtin_amdgcn_mfma_f32_16x16x32_bf16(pf, vf, oacc[dj], 0, 0, 0);
      }
    }
    __builtin_amdgcn_s_setprio(0);
  }
  // epilogue
#pragma unroll
  for (int r = 0; r < 4; ++r) {
    float inv = 1.f / l_run[r];
    long orow = (long)(b * SEQ + qt * 64 + wave * 16 + lhi * 4 + r);
#pragma unroll
    for (int dj = 0; dj < 8; ++dj)
      out[orow * (NH * HD) + h * HD + dj * 16 + l16] = (bf16)(oacc[dj][r] * inv);
  }
}

extern "C" void kernel_launch(void* const* d_in, const int* in_sizes, int n_in,
                              void* d_out, int out_size, void* d_ws, size_t ws_size,
                              hipStream_t stream) {
  const int* positions = (const int*)d_in[0];
  const float* hidden = (const float*)d_in[1];
  const float* wq = (const float*)d_in[2];
  const float* wk = (const float*)d_in[3];
  const float* wv = (const float*)d_in[4];
  const float* wo = (const float*)d_in[5];
  float* out = (float*)d_out;
  char* ws = (char*)d_ws;

  const size_t SZ_H = (size_t)MROWS * HID * 2;
  const size_t SZ_WQKV = (size_t)QKVN * HID * 2;
  const size_t SZ_WO = (size_t)HID * HID * 2;
  bf16* h_bf = (bf16*)(ws);
  bf16* wqkvT = (bf16*)(ws + SZ_H);
  bf16* woT = (bf16*)(ws + SZ_H + SZ_WQKV);
  bf16* qkv = (bf16*)(ws + SZ_H + SZ_WQKV + SZ_WO);
  bf16* attn = h_bf;
  bf16* vtbuf = wqkvT;

  const int GEMM_SMEM = 3 * 24576 * 2;   // 147456 B
  auto* g1 = gemm256<bf16>;
  auto* g2 = gemm256<float>;
  hipFuncSetAttribute(reinterpret_cast<const void*>(g1),
                      hipFuncAttributeMaxDynamicSharedMemorySize, GEMM_SMEM);
  hipFuncSetAttribute(reinterpret_cast<const void*>(g2),
                      hipFuncAttributeMaxDynamicSharedMemorySize, GEMM_SMEM);

  h2b_kernel<<<(MROWS * (long)HID) / (256 * 4), 256, 0, stream>>>(hidden, h_bf);
  dim3 t32(32, 8);
  wtrans_kernel<<<dim3(HID / 32, HID / 32), t32, 0, stream>>>(wq, wqkvT, HID, HID);
  wtrans_kernel<<<dim3(1024 / 32, HID / 32), t32, 0, stream>>>(wk, wqkvT + (long)4096 * HID, HID, 1024);
  wtrans_kernel<<<dim3(1024 / 32, HID / 32), t32, 0, stream>>>(wv, wqkvT + (long)5120 * HID, HID, 1024);
  wtrans_kernel<<<dim3(HID / 32, HID / 32), t32, 0, stream>>>(wo, woT, HID, HID);
  gemm256<bf16><<<dim3(QKVN / 128, MROWS / 256), 512, GEMM_SMEM, stream>>>(h_bf, wqkvT, qkv, MROWS, QKVN, HID);
  rope_kernel<<<(MROWS * 40 * 64) / 256, 256, 0, stream>>>(qkv, positions);
  vtrans_kernel<<<dim3(SEQ / 32, HD / 32, BATCH * NKVH), t32, 0, stream>>>(qkv, vtbuf);
  attn_kernel<<<dim3(SEQ / 64, NH, BATCH), 256, 0, stream>>>(qkv, vtbuf, attn);
  gemm256<float><<<dim3(HID / 128, MROWS / 256), 512, GEMM_SMEM, stream>>>(attn, woT, out, MROWS, HID, HID);
}

// Round 5
// 701.535 us; speedup vs baseline: 1.8706x; 1.8706x over previous
//
#include <hip/hip_runtime.h>
#include <cstdint>

typedef __bf16 bf16;
typedef __attribute__((ext_vector_type(4))) __bf16 bf16x4;
typedef __attribute__((ext_vector_type(8))) __bf16 bf16x8;
typedef __attribute__((ext_vector_type(4))) float f32x4;

#define DEVI __device__ __forceinline__

#define BATCH 2
#define SEQ 2048
#define HID 4096
#define NH 32
#define NKVH 8
#define HD 128
#define QKVN 6144
#define MROWS 4096
#define ATT_SCALE 0.08838834764831845f
// scale folded with log2(e) so softmax uses exp2 directly
#define QSCALE (0.08838834764831845f * 1.4426950408889634f)

DEVI void gload_lds16(const bf16* g, bf16* l) {
  __builtin_amdgcn_global_load_lds(
      (__attribute__((address_space(1))) void*)(g),
      (__attribute__((address_space(3))) void*)(l), 16, 0, 0);
}

// ---------------- elementwise f32 -> bf16 ----------------
__global__ void h2b_kernel(const float* __restrict__ in, bf16* __restrict__ out) {
  long i = ((long)blockIdx.x * 256 + threadIdx.x) * 4;
  float4 v = *(const float4*)(in + i);
  bf16x4 o;
  o[0] = (bf16)v.x; o[1] = (bf16)v.y; o[2] = (bf16)v.z; o[3] = (bf16)v.w;
  *(bf16x4*)(out + i) = o;
}

// ---------------- transpose-convert weight: in (K,N) f32 -> out (N,K) bf16 ----------------
__global__ void wtrans_kernel(const float* __restrict__ in, bf16* __restrict__ out,
                              int K, int N) {
  __shared__ float t[32][33];
  int n0 = blockIdx.x * 32, k0 = blockIdx.y * 32;
  int tx = threadIdx.x, ty = threadIdx.y; // (32,8)
#pragma unroll
  for (int r = 0; r < 4; ++r) {
    int k = ty + r * 8;
    t[k][tx] = in[(long)(k0 + k) * N + n0 + tx];
  }
  __syncthreads();
#pragma unroll
  for (int r = 0; r < 4; ++r) {
    int n = ty + r * 8;
    out[(long)(n0 + n) * K + k0 + tx] = (bf16)t[tx][n];
  }
}

// ---------------- RoPE in-place on q,k columns of qkv ----------------
__global__ void rope_kernel(bf16* __restrict__ qkv, const int* __restrict__ pos) {
  long idx = (long)blockIdx.x * 256 + threadIdx.x;
  if (idx >= (long)MROWS * 40 * 64) return;
  int d = idx & 63;
  long t = idx >> 6;
  int hh = (int)(t % 40);
  int row = (int)(t / 40);
  int colb = hh < NH ? hh * HD : NH * HD + (hh - NH) * HD;
  float p = (float)pos[row];
  float inv_freq = exp2f((float)d * -0.2076205059304601f);
  float ang = p * inv_freq;
  float sn = sinf(ang), cs = cosf(ang);
  bf16* base = qkv + (long)row * QKVN + colb + d;
  float x1 = (float)base[0], x2 = (float)base[64];
  base[0] = (bf16)(x1 * cs - x2 * sn);
  base[64] = (bf16)(x2 * cs + x1 * sn);
}

// ---------------- transpose V: qkv v-cols -> vt (b,kvh,D,S) ----------------
__global__ void vtrans_kernel(const bf16* __restrict__ qkv, bf16* __restrict__ vt) {
  __shared__ bf16 t[32][33];
  int s0 = blockIdx.x * 32, d0 = blockIdx.y * 32, bk = blockIdx.z;
  int b = bk >> 3, kvh = bk & 7;
  int tx = threadIdx.x, ty = threadIdx.y; // (32,8)
#pragma unroll
  for (int r = 0; r < 4; ++r) {
    int s = ty + r * 8;
    t[s][tx] = qkv[(long)(b * SEQ + s0 + s) * QKVN + 5120 + kvh * HD + d0 + tx];
  }
  __syncthreads();
#pragma unroll
  for (int r = 0; r < 4; ++r) {
    int d = ty + r * 8;
    vt[((long)bk * HD + d0 + d) * SEQ + s0 + tx] = t[tx][d];
  }
}

// ---------------- pipelined GEMM: C(M,N) = A(M,K) x BT(N,K)^T ----------------
// 256x128 tile, BK=64, 8 waves (4M x 2N), wave-tile 64x64. Ring-3 LDS.
template <typename OutT>
__global__ __launch_bounds__(512, 2)
void gemm256(const bf16* __restrict__ A, const bf16* __restrict__ BT,
             OutT* __restrict__ C, int M, int N, int K) {
  extern __shared__ __align__(16) bf16 lds[];
  const int tid = threadIdx.x;
  const int lane = tid & 63, wave = tid >> 6;
  const int wm = wave >> 1, wn = wave & 1;
  const int l16 = lane & 15, lhi = lane >> 4;
  const int nwg = gridDim.x * gridDim.y;
  const int bid = blockIdx.y * gridDim.x + blockIdx.x;
  const int cpx = nwg >> 3;
  const int swz = (bid & 7) * cpx + (bid >> 3);
  const int bx = swz % gridDim.x, by = swz / gridDim.x;
  const long bm0 = (long)by * 256, bn0 = (long)bx * 128;

  const int srow8 = lane >> 3;
  const int scol = (lane & 7) ^ srow8;

  const int NT = K >> 6;
  f32x4 acc[4][4] = {};

  auto stage = [&](int slot, int t) {
    const long k0 = (long)t << 6;
    bf16* dst = lds + slot * 24576;
#pragma unroll
    for (int i = 0; i < 4; ++i) {
      int r = (wave * 4 + i) * 8 + srow8;
      gload_lds16(A + (bm0 + r) * K + k0 + scol * 8,
                  dst + (wave * 4 + i) * 512 + lane * 8);
    }
#pragma unroll
    for (int i = 0; i < 2; ++i) {
      int r = (wave * 2 + i) * 8 + srow8;
      gload_lds16(BT + (bn0 + r) * K + k0 + scol * 8,
                  dst + 16384 + (wave * 2 + i) * 512 + lane * 8);
    }
  };

  stage(0, 0);
  stage(1, 1);

  for (int t = 0; t < NT; ++t) {
    asm volatile("s_waitcnt vmcnt(6)" ::: "memory");
    __builtin_amdgcn_s_barrier();
    __builtin_amdgcn_sched_barrier(0);
    const int nxt = (t + 2 < NT) ? t + 2 : NT - 1;
    stage((t + 2) % 3, nxt);
    const bf16* As = lds + (t % 3) * 24576;
    const bf16* Bs = As + 16384;
#pragma unroll
    for (int kk = 0; kk < 2; ++kk) {
      bf16x8 af[4], bw[4];
#pragma unroll
      for (int i = 0; i < 4; ++i) {
        int ar = wm * 64 + i * 16 + l16;
        af[i] = *(const bf16x8*)(As + ar * 64 + (((kk * 4 + lhi) ^ (ar & 7))) * 8);
        int br = wn * 64 + i * 16 + l16;
        bw[i] = *(const bf16x8*)(Bs + br * 64 + (((kk * 4 + lhi) ^ (br & 7))) * 8);
      }
      __builtin_amdgcn_s_setprio(1);
#pragma unroll
      for (int i = 0; i < 4; ++i)
#pragma unroll
        for (int j = 0; j < 4; ++j)
          acc[i][j] = __builtin_amdgcn_mfma_f32_16x16x32_bf16(af[i], bw[j], acc[i][j], 0, 0, 0);
      __builtin_amdgcn_s_setprio(0);
    }
  }
  asm volatile("s_waitcnt vmcnt(0)" ::: "memory");
#pragma unroll
  for (int i = 0; i < 4; ++i)
#pragma unroll
    for (int r = 0; r < 4; ++r) {
      long grow = bm0 + wm * 64 + i * 16 + lhi * 4 + r;
#pragma unroll
      for (int j = 0; j < 4; ++j) {
        long gcol = bn0 + wn * 64 + j * 16 + l16;
        C[grow * N + gcol] = (OutT)acc[i][j][r];
      }
    }
}

// ---------------- flash attention: staged K/V dbuf + swapped-QK^T lane-local softmax ----
// grid (qt reversed, h, b), 256 threads = 4 waves x 16 q-rows.
// QK^T computed as mfma(K, Q) so the score tile lands TRANSPOSED: each lane holds
// S[k = kv0 + c*16 + lhi*4 + r][q = l16] — the softmax row-reduce is 16 in-register
// values + 2 shfl_xor (vs 32 shfls in the row-major layout). m/l are per-lane scalars.
__global__ __launch_bounds__(256)
void attn_kernel(const bf16* __restrict__ qkv, const bf16* __restrict__ vt,
                 bf16* __restrict__ out) {
  __shared__ __align__(16) bf16 Ks[2][64 * 128];
  __shared__ __align__(16) bf16 Vs[2][128 * 64];
  __shared__ __align__(16) bf16 Ps[4][16 * 64];
  const int qt = (gridDim.x - 1) - blockIdx.x;  // longest blocks first
  const int h = blockIdx.y, b = blockIdx.z;
  const int kvh = h >> 2;
  const int tid = threadIdx.x, lane = tid & 63, wave = tid >> 6;
  const int l16 = lane & 15, lhi = lane >> 4;

  // Q fragments, pre-scaled by ATT_SCALE*log2(e)
  bf16x8 qf[4];
  const bf16* qbase = qkv + (long)(b * SEQ + qt * 64 + wave * 16 + l16) * QKVN + h * HD + lhi * 8;
#pragma unroll
  for (int di = 0; di < 4; ++di) {
    bf16x8 raw = *(const bf16x8*)(qbase + di * 32);
    bf16x8 sc;
#pragma unroll
    for (int j = 0; j < 8; ++j) sc[j] = (bf16)((float)raw[j] * QSCALE);
    qf[di] = sc;
  }

  f32x4 oacc[8] = {};
  float m_run = -1e30f, l_run = 0.f;
  const int qg = qt * 64 + wave * 16 + l16;  // this lane's q row (global)
  const int kloc = lhi * 4;                  // lane's k sub-offset

  auto stageKV = [&](int buf, int step) {
    const int kv0 = step * 64;
    bf16* kd = Ks[buf];
    bf16* vd = Vs[buf];
#pragma unroll
    for (int c = 0; c < 4; ++c) {
      int chunk = wave * 4 + c;
      int krow = chunk * 4 + lhi;
      int kc16 = l16 ^ (krow & 7);
      gload_lds16(qkv + (long)(b * SEQ + kv0 + krow) * QKVN + 4096 + kvh * HD + kc16 * 8,
                  kd + chunk * 512);
      int vrow = chunk * 8 + (lane >> 3);
      int vc16 = (lane & 7) ^ (vrow & 7);
      gload_lds16(vt + ((long)(b * NKVH + kvh) * HD + vrow) * SEQ + kv0 + vc16 * 8,
                  vd + chunk * 512);
    }
  };

  const int nsteps = qt + 1;
  stageKV(0, 0);
  __syncthreads();

  for (int step = 0; step < nsteps; ++step) {
    const int kv0 = step * 64;
    const int cur = step & 1;
    if (step + 1 < nsteps) stageKV(cur ^ 1, step + 1);  // prefetch hides under compute
    const bf16* Kc = Ks[cur];
    const bf16* Vc = Vs[cur];

    // S^T = K * Q^T (swapped operands): s[c][r] = S[k=kv0+c*16+lhi*4+r][q=qg]
    f32x4 s[4];
    __builtin_amdgcn_s_setprio(1);
#pragma unroll
    for (int c = 0; c < 4; ++c) {
      s[c] = (f32x4){0.f, 0.f, 0.f, 0.f};
      int krow2 = c * 16 + l16;
#pragma unroll
      for (int di = 0; di < 4; ++di) {
        bf16x8 kf = *(const bf16x8*)(Kc + krow2 * 128 + (((di * 4 + lhi) ^ (krow2 & 7))) * 8);
        s[c] = __builtin_amdgcn_mfma_f32_16x16x32_bf16(kf, qf[di], s[c], 0, 0, 0);
      }
    }
    __builtin_amdgcn_s_setprio(0);
    // causal mask (scale already folded into qf)
#pragma unroll
    for (int c = 0; c < 4; ++c)
#pragma unroll
      for (int r = 0; r < 4; ++r) {
        int kcol = kv0 + c * 16 + kloc + r;
        if (kcol > qg) s[c][r] = -1e30f;
      }
    // per-lane online softmax over 16 regs, combine across lhi groups (2 shfl)
    float mloc = s[0][0];
#pragma unroll
    for (int c = 0; c < 4; ++c)
#pragma unroll
      for (int r = 0; r < 4; ++r) mloc = fmaxf(mloc, s[c][r]);
    mloc = fmaxf(mloc, __shfl_xor(mloc, 16, 64));
    mloc = fmaxf(mloc, __shfl_xor(mloc, 32, 64));
    float mn = fmaxf(m_run, mloc);
    float alpha = exp2f(m_run - mn);
    m_run = mn;
    float sm = 0.f;
    bf16x4 pb[4];
#pragma unroll
    for (int c = 0; c < 4; ++c)
#pragma unroll
      for (int r = 0; r < 4; ++r) {
        float p = exp2f(s[c][r] - mn);
        sm += p;
        pb[c][r] = (bf16)p;
      }
    sm += __shfl_xor(sm, 16, 64);
    sm += __shfl_xor(sm, 32, 64);
    l_run = l_run * alpha + sm;
    // packed P write: row q=l16, logical 16B-slot c*2+(lhi>>1), phys ^(l16&7), 8B half lhi&1
#pragma unroll
    for (int c = 0; c < 4; ++c) {
      int sl = (c * 2 + (lhi >> 1)) ^ (l16 & 7);
      *(bf16x4*)(&Ps[wave][l16 * 64 + sl * 8 + (lhi & 1) * 4]) = pb[c];
    }
    // redistribute alpha to O-accumulator layout (row q = lhi*4 + r)
    float a_o[4];
#pragma unroll
    for (int r = 0; r < 4; ++r) a_o[r] = __shfl(alpha, kloc + r, 64);
#pragma unroll
    for (int dj = 0; dj < 8; ++dj)
#pragma unroll
      for (int r = 0; r < 4; ++r) oacc[dj][r] *= a_o[r];
    // PV: O[16][128] += P[16][64] x V[64][128]
    __builtin_amdgcn_s_setprio(1);
#pragma unroll
    for (int kh = 0; kh < 2; ++kh) {
      bf16x8 pf = *(const bf16x8*)(&Ps[wave][l16 * 64 + (((kh * 4 + lhi) ^ (l16 & 7))) * 8]);
#pragma unroll
      for (int dj = 0; dj < 8; ++dj) {
        int vrow2 = dj * 16 + l16;
        bf16x8 vf = *(const bf16x8*)(Vc + vrow2 * 64 + (((kh * 4 + lhi) ^ (vrow2 & 7))) * 8);
        oacc[dj] = __builtin_amdgcn_mfma_f32_16x16x32_bf16(pf, vf, oacc[dj], 0, 0, 0);
      }
    }
    __builtin_amdgcn_s_setprio(0);
    __syncthreads();  // drains prefetch + protects dbuf swap
  }
  // epilogue: fetch l for rows q = lhi*4+r, normalize, store
  float linv[4];
#pragma unroll
  for (int r = 0; r < 4; ++r) linv[r] = 1.f / __shfl(l_run, kloc + r, 64);
#pragma unroll
  for (int r = 0; r < 4; ++r) {
    long orow = (long)(b * SEQ + qt * 64 + wave * 16 + lhi * 4 + r);
#pragma unroll
    for (int dj = 0; dj < 8; ++dj)
      out[orow * (NH * HD) + h * HD + dj * 16 + l16] = (bf16)(oacc[dj][r] * linv[r]);
  }
}

extern "C" void kernel_launch(void* const* d_in, const int* in_sizes, int n_in,
                              void* d_out, int out_size, void* d_ws, size_t ws_size,
                              hipStream_t stream) {
  const int* positions = (const int*)d_in[0];
  const float* hidden = (const float*)d_in[1];
  const float* wq = (const float*)d_in[2];
  const float* wk = (const float*)d_in[3];
  const float* wv = (const float*)d_in[4];
  const float* wo = (const float*)d_in[5];
  float* out = (float*)d_out;
  char* ws = (char*)d_ws;

  const size_t SZ_H = (size_t)MROWS * HID * 2;
  const size_t SZ_WQKV = (size_t)QKVN * HID * 2;
  const size_t SZ_WO = (size_t)HID * HID * 2;
  bf16* h_bf = (bf16*)(ws);
  bf16* wqkvT = (bf16*)(ws + SZ_H);
  bf16* woT = (bf16*)(ws + SZ_H + SZ_WQKV);
  bf16* qkv = (bf16*)(ws + SZ_H + SZ_WQKV + SZ_WO);
  bf16* attn = h_bf;
  bf16* vtbuf = wqkvT;

  const int GEMM_SMEM = 3 * 24576 * 2;   // 147456 B
  auto* g1 = gemm256<bf16>;
  auto* g2 = gemm256<float>;
  hipFuncSetAttribute(reinterpret_cast<const void*>(g1),
                      hipFuncAttributeMaxDynamicSharedMemorySize, GEMM_SMEM);
  hipFuncSetAttribute(reinterpret_cast<const void*>(g2),
                      hipFuncAttributeMaxDynamicSharedMemorySize, GEMM_SMEM);

  h2b_kernel<<<(MROWS * (long)HID) / (256 * 4), 256, 0, stream>>>(hidden, h_bf);
  dim3 t32(32, 8);
  wtrans_kernel<<<dim3(HID / 32, HID / 32), t32, 0, stream>>>(wq, wqkvT, HID, HID);
  wtrans_kernel<<<dim3(1024 / 32, HID / 32), t32, 0, stream>>>(wk, wqkvT + (long)4096 * HID, HID, 1024);
  wtrans_kernel<<<dim3(1024 / 32, HID / 32), t32, 0, stream>>>(wv, wqkvT + (long)5120 * HID, HID, 1024);
  wtrans_kernel<<<dim3(HID / 32, HID / 32), t32, 0, stream>>>(wo, woT, HID, HID);
  gemm256<bf16><<<dim3(QKVN / 128, MROWS / 256), 512, GEMM_SMEM, stream>>>(h_bf, wqkvT, qkv, MROWS, QKVN, HID);
  rope_kernel<<<(MROWS * 40 * 64) / 256, 256, 0, stream>>>(qkv, positions);
  vtrans_kernel<<<dim3(SEQ / 32, HD / 32, BATCH * NKVH), t32, 0, stream>>>(qkv, vtbuf);
  attn_kernel<<<dim3(SEQ / 64, NH, BATCH), 256, 0, stream>>>(qkv, vtbuf, attn);
  gemm256<float><<<dim3(HID / 128, MROWS / 256), 512, GEMM_SMEM, stream>>>(attn, woT, out, MROWS, HID, HID);
}

// Round 6
// 554.928 us; speedup vs baseline: 2.3648x; 1.2642x over previous
//
#include <hip/hip_runtime.h>
#include <cstdint>

typedef __bf16 bf16;
typedef __attribute__((ext_vector_type(4))) __bf16 bf16x4;
typedef __attribute__((ext_vector_type(8))) __bf16 bf16x8;
typedef __attribute__((ext_vector_type(4))) float f32x4;

#define DEVI __device__ __forceinline__

#define BATCH 2
#define SEQ 2048
#define HID 4096
#define NH 32
#define NKVH 8
#define HD 128
#define QKVN 6144
#define MROWS 4096
#define ATT_SCALE 0.08838834764831845f
// scale folded with log2(e) so softmax uses exp2 directly
#define QSCALE (0.08838834764831845f * 1.4426950408889634f)

DEVI void gload_lds16(const bf16* g, bf16* l) {
  __builtin_amdgcn_global_load_lds(
      (__attribute__((address_space(1))) void*)(g),
      (__attribute__((address_space(3))) void*)(l), 16, 0, 0);
}

// ---------------- elementwise f32 -> bf16 ----------------
__global__ void h2b_kernel(const float* __restrict__ in, bf16* __restrict__ out) {
  long i = ((long)blockIdx.x * 256 + threadIdx.x) * 4;
  float4 v = *(const float4*)(in + i);
  bf16x4 o;
  o[0] = (bf16)v.x; o[1] = (bf16)v.y; o[2] = (bf16)v.z; o[3] = (bf16)v.w;
  *(bf16x4*)(out + i) = o;
}

// ---------------- transpose-convert weight: in (K,N) f32 -> out (N,K) bf16 ----------------
__global__ void wtrans_kernel(const float* __restrict__ in, bf16* __restrict__ out,
                              int K, int N) {
  __shared__ float t[32][33];
  int n0 = blockIdx.x * 32, k0 = blockIdx.y * 32;
  int tx = threadIdx.x, ty = threadIdx.y; // (32,8)
#pragma unroll
  for (int r = 0; r < 4; ++r) {
    int k = ty + r * 8;
    t[k][tx] = in[(long)(k0 + k) * N + n0 + tx];
  }
  __syncthreads();
#pragma unroll
  for (int r = 0; r < 4; ++r) {
    int n = ty + r * 8;
    out[(long)(n0 + n) * K + k0 + tx] = (bf16)t[tx][n];
  }
}

// ---------------- RoPE in-place on q,k columns of qkv ----------------
__global__ void rope_kernel(bf16* __restrict__ qkv, const int* __restrict__ pos) {
  long idx = (long)blockIdx.x * 256 + threadIdx.x;
  if (idx >= (long)MROWS * 40 * 64) return;
  int d = idx & 63;
  long t = idx >> 6;
  int hh = (int)(t % 40);
  int row = (int)(t / 40);
  int colb = hh < NH ? hh * HD : NH * HD + (hh - NH) * HD;
  float p = (float)pos[row];
  float inv_freq = exp2f((float)d * -0.2076205059304601f);
  float ang = p * inv_freq;
  float sn = sinf(ang), cs = cosf(ang);
  bf16* base = qkv + (long)row * QKVN + colb + d;
  float x1 = (float)base[0], x2 = (float)base[64];
  base[0] = (bf16)(x1 * cs - x2 * sn);
  base[64] = (bf16)(x2 * cs + x1 * sn);
}

// ---------------- transpose V: qkv v-cols -> vt (b,kvh,D,S) ----------------
__global__ void vtrans_kernel(const bf16* __restrict__ qkv, bf16* __restrict__ vt) {
  __shared__ bf16 t[32][33];
  int s0 = blockIdx.x * 32, d0 = blockIdx.y * 32, bk = blockIdx.z;
  int b = bk >> 3, kvh = bk & 7;
  int tx = threadIdx.x, ty = threadIdx.y; // (32,8)
#pragma unroll
  for (int r = 0; r < 4; ++r) {
    int s = ty + r * 8;
    t[s][tx] = qkv[(long)(b * SEQ + s0 + s) * QKVN + 5120 + kvh * HD + d0 + tx];
  }
  __syncthreads();
#pragma unroll
  for (int r = 0; r < 4; ++r) {
    int d = ty + r * 8;
    vt[((long)bk * HD + d0 + d) * SEQ + s0 + tx] = t[tx][d];
  }
}

// ---------------- pipelined GEMM: C(M,N) = A(M,K) x BT(N,K)^T ----------------
// 256x128 tile, BK=64, 8 waves (4M x 2N), wave-tile 64x64. Ring-3 LDS.
template <typename OutT>
__global__ __launch_bounds__(512, 2)
void gemm256(const bf16* __restrict__ A, const bf16* __restrict__ BT,
             OutT* __restrict__ C, int M, int N, int K) {
  extern __shared__ __align__(16) bf16 lds[];
  const int tid = threadIdx.x;
  const int lane = tid & 63, wave = tid >> 6;
  const int wm = wave >> 1, wn = wave & 1;
  const int l16 = lane & 15, lhi = lane >> 4;
  const int nwg = gridDim.x * gridDim.y;
  const int bid = blockIdx.y * gridDim.x + blockIdx.x;
  const int cpx = nwg >> 3;
  const int swz = (bid & 7) * cpx + (bid >> 3);
  const int bx = swz % gridDim.x, by = swz / gridDim.x;
  const long bm0 = (long)by * 256, bn0 = (long)bx * 128;

  const int srow8 = lane >> 3;
  const int scol = (lane & 7) ^ srow8;

  const int NT = K >> 6;
  f32x4 acc[4][4] = {};

  auto stage = [&](int slot, int t) {
    const long k0 = (long)t << 6;
    bf16* dst = lds + slot * 24576;
#pragma unroll
    for (int i = 0; i < 4; ++i) {
      int r = (wave * 4 + i) * 8 + srow8;
      gload_lds16(A + (bm0 + r) * K + k0 + scol * 8,
                  dst + (wave * 4 + i) * 512 + lane * 8);
    }
#pragma unroll
    for (int i = 0; i < 2; ++i) {
      int r = (wave * 2 + i) * 8 + srow8;
      gload_lds16(BT + (bn0 + r) * K + k0 + scol * 8,
                  dst + 16384 + (wave * 2 + i) * 512 + lane * 8);
    }
  };

  stage(0, 0);
  stage(1, 1);

  for (int t = 0; t < NT; ++t) {
    asm volatile("s_waitcnt vmcnt(6)" ::: "memory");
    __builtin_amdgcn_s_barrier();
    __builtin_amdgcn_sched_barrier(0);
    const int nxt = (t + 2 < NT) ? t + 2 : NT - 1;
    stage((t + 2) % 3, nxt);
    const bf16* As = lds + (t % 3) * 24576;
    const bf16* Bs = As + 16384;
#pragma unroll
    for (int kk = 0; kk < 2; ++kk) {
      bf16x8 af[4], bw[4];
#pragma unroll
      for (int i = 0; i < 4; ++i) {
        int ar = wm * 64 + i * 16 + l16;
        af[i] = *(const bf16x8*)(As + ar * 64 + (((kk * 4 + lhi) ^ (ar & 7))) * 8);
        int br = wn * 64 + i * 16 + l16;
        bw[i] = *(const bf16x8*)(Bs + br * 64 + (((kk * 4 + lhi) ^ (br & 7))) * 8);
      }
      __builtin_amdgcn_s_setprio(1);
#pragma unroll
      for (int i = 0; i < 4; ++i)
#pragma unroll
        for (int j = 0; j < 4; ++j)
          acc[i][j] = __builtin_amdgcn_mfma_f32_16x16x32_bf16(af[i], bw[j], acc[i][j], 0, 0, 0);
      __builtin_amdgcn_s_setprio(0);
    }
  }
  asm volatile("s_waitcnt vmcnt(0)" ::: "memory");
#pragma unroll
  for (int i = 0; i < 4; ++i)
#pragma unroll
    for (int r = 0; r < 4; ++r) {
      long grow = bm0 + wm * 64 + i * 16 + lhi * 4 + r;
#pragma unroll
      for (int j = 0; j < 4; ++j) {
        long gcol = bn0 + wn * 64 + j * 16 + l16;
        C[grow * N + gcol] = (OutT)acc[i][j][r];
      }
    }
}

// ---------------- flash attention: work-balanced paired chunks ----------------
// 512 threads = 8 waves x 16 q-rows = 128-row chunk. Each block processes chunk
// pi AND chunk 15-pi sequentially: total K/V steps = (2pi+2)+(32-2pi) = 34 for
// EVERY block. Grid = 8x32x2 = 512 equal blocks = exactly 2/CU: one balanced
// round, no tail. Swapped-QK^T lane-local softmax (lane holds S^T[k][q=l16]),
// defer-rescale (T13), K/V double-buffered via global_load_lds with XOR swizzle.
__global__ __launch_bounds__(512, 4)
void attn_kernel(const bf16* __restrict__ qkv, const bf16* __restrict__ vt,
                 bf16* __restrict__ out) {
  extern __shared__ __align__(16) bf16 smem[];
  // layout (elems): K0 0, K1 8192, V0 16384, V1 24576, P 32768 (8 x 1024)
  const int pi = blockIdx.x, h = blockIdx.y, b = blockIdx.z;
  const int kvh = h >> 2;
  const int tid = threadIdx.x, lane = tid & 63, wave = tid >> 6;
  const int l16 = lane & 15, lhi = lane >> 4;
  const int kloc = lhi * 4;
  bf16* Pw = smem + 32768 + wave * 1024;

  const bf16* kpan = qkv + (long)(b * SEQ) * QKVN + 4096 + kvh * HD;
  const bf16* vpan = vt + (long)(b * NKVH + kvh) * HD * SEQ;

  auto stageKV = [&](int buf, int step) {
    const int kv0 = step * 64;
    bf16* kd = smem + buf * 8192;
    bf16* vd = smem + 16384 + buf * 8192;
#pragma unroll
    for (int i = 0; i < 2; ++i) {
      int kr = wave * 8 + i * 4 + lhi;                 // K row this lane sources
      gload_lds16(kpan + (long)(kv0 + kr) * QKVN + (l16 ^ (kr & 7)) * 8,
                  kd + (wave * 8 + i * 4) * 128);      // uniform base; lanes land +lane*16B
      int vr = wave * 16 + i * 8 + (lane >> 3);        // V^T row this lane sources
      gload_lds16(vpan + (long)vr * SEQ + kv0 + ((lane & 7) ^ (vr & 7)) * 8,
                  vd + (wave * 16 + i * 8) * 64);
    }
  };

  auto process_chunk = [&](int q0, int nsteps) {
    // Q fragments, pre-scaled by ATT_SCALE*log2(e)
    bf16x8 qf[4];
    const bf16* qb = qkv + (long)(b * SEQ + q0 + wave * 16 + l16) * QKVN + h * HD + lhi * 8;
#pragma unroll
    for (int di = 0; di < 4; ++di) {
      bf16x8 raw = *(const bf16x8*)(qb + di * 32);
      bf16x8 sc;
#pragma unroll
      for (int j = 0; j < 8; ++j) sc[j] = (bf16)((float)raw[j] * QSCALE);
      qf[di] = sc;
    }
    f32x4 oacc[8] = {};
    float m_run = -1e30f, l_run = 0.f;
    const int qg = q0 + wave * 16 + l16;   // this lane's q row (softmax layout)

    stageKV(0, 0);
    __syncthreads();

    for (int step = 0; step < nsteps; ++step) {
      const int kv0 = step * 64;
      const int cur = step & 1;
      if (step + 1 < nsteps) stageKV(cur ^ 1, step + 1);  // prefetch hides under compute
      const bf16* Kc = smem + cur * 8192;
      const bf16* Vc = smem + 16384 + cur * 8192;

      // S^T = K * Q^T: s[c][r] = S[k=kv0+c*16+kloc+r][q=qg]
      f32x4 s[4];
      __builtin_amdgcn_s_setprio(1);
#pragma unroll
      for (int c = 0; c < 4; ++c) {
        s[c] = (f32x4){0.f, 0.f, 0.f, 0.f};
        int kr = c * 16 + l16;
#pragma unroll
        for (int di = 0; di < 4; ++di) {
          bf16x8 kf = *(const bf16x8*)(Kc + kr * 128 + (((di * 4 + lhi) ^ (kr & 7))) * 8);
          s[c] = __builtin_amdgcn_mfma_f32_16x16x32_bf16(kf, qf[di], s[c], 0, 0, 0);
        }
      }
      __builtin_amdgcn_s_setprio(0);
      // causal mask (scale already folded into qf)
#pragma unroll
      for (int c = 0; c < 4; ++c)
#pragma unroll
        for (int r = 0; r < 4; ++r) {
          int kcol = kv0 + c * 16 + kloc + r;
          if (kcol > qg) s[c][r] = -1e30f;
        }
      // per-lane max over 16 regs + 2 shfl to combine lhi groups
      float mloc = s[0][0];
#pragma unroll
      for (int c = 0; c < 4; ++c)
#pragma unroll
        for (int r = 0; r < 4; ++r) mloc = fmaxf(mloc, s[c][r]);
      mloc = fmaxf(mloc, __shfl_xor(mloc, 16, 64));
      mloc = fmaxf(mloc, __shfl_xor(mloc, 32, 64));
      // defer-rescale (T13): P bounded by 2^8, skip O-rescale when max stable
      bool skip = __all(mloc - m_run <= 8.0f);
      float alpha = 1.f;
      if (!skip) {
        float mn = fmaxf(m_run, mloc);
        alpha = exp2f(m_run - mn);
        m_run = mn;
      }
      float sm = 0.f;
      bf16x4 pb[4];
#pragma unroll
      for (int c = 0; c < 4; ++c)
#pragma unroll
        for (int r = 0; r < 4; ++r) {
          float p = exp2f(s[c][r] - m_run);
          sm += p;
          pb[c][r] = (bf16)p;
        }
      sm += __shfl_xor(sm, 16, 64);
      sm += __shfl_xor(sm, 32, 64);
      l_run = l_run * alpha + sm;
      // packed P write (swizzled slots)
#pragma unroll
      for (int c = 0; c < 4; ++c) {
        int sl = (c * 2 + (lhi >> 1)) ^ (l16 & 7);
        *(bf16x4*)(Pw + l16 * 64 + sl * 8 + (lhi & 1) * 4) = pb[c];
      }
      if (!skip) {
        float a_o[4];
#pragma unroll
        for (int r = 0; r < 4; ++r) a_o[r] = __shfl(alpha, kloc + r, 64);
#pragma unroll
        for (int dj = 0; dj < 8; ++dj)
#pragma unroll
          for (int r = 0; r < 4; ++r) oacc[dj][r] *= a_o[r];
      }
      // PV: O[16][128] += P[16][64] x V[64][128]
      __builtin_amdgcn_s_setprio(1);
#pragma unroll
      for (int kh = 0; kh < 2; ++kh) {
        bf16x8 pf = *(const bf16x8*)(Pw + l16 * 64 + (((kh * 4 + lhi) ^ (l16 & 7))) * 8);
#pragma unroll
        for (int dj = 0; dj < 8; ++dj) {
          int vr = dj * 16 + l16;
          bf16x8 vf = *(const bf16x8*)(Vc + vr * 64 + (((kh * 4 + lhi) ^ (vr & 7))) * 8);
          oacc[dj] = __builtin_amdgcn_mfma_f32_16x16x32_bf16(pf, vf, oacc[dj], 0, 0, 0);
        }
      }
      __builtin_amdgcn_s_setprio(0);
      __syncthreads();  // drains prefetch + protects dbuf swap
    }
    // epilogue: fetch l for rows q = lhi*4+r, normalize, store
    float linv[4];
#pragma unroll
    for (int r = 0; r < 4; ++r) linv[r] = 1.f / __shfl(l_run, kloc + r, 64);
#pragma unroll
    for (int r = 0; r < 4; ++r) {
      long orow = (long)(b * SEQ + q0 + wave * 16 + lhi * 4 + r);
#pragma unroll
      for (int dj = 0; dj < 8; ++dj)
        out[orow * (NH * HD) + h * HD + dj * 16 + l16] = (bf16)(oacc[dj][r] * linv[r]);
    }
  };

  process_chunk(pi * 128, 2 * pi + 2);          // light chunk
  process_chunk((15 - pi) * 128, 32 - 2 * pi);  // heavy chunk: total 34 steps/block
}

extern "C" void kernel_launch(void* const* d_in, const int* in_sizes, int n_in,
                              void* d_out, int out_size, void* d_ws, size_t ws_size,
                              hipStream_t stream) {
  const int* positions = (const int*)d_in[0];
  const float* hidden = (const float*)d_in[1];
  const float* wq = (const float*)d_in[2];
  const float* wk = (const float*)d_in[3];
  const float* wv = (const float*)d_in[4];
  const float* wo = (const float*)d_in[5];
  float* out = (float*)d_out;
  char* ws = (char*)d_ws;

  const size_t SZ_H = (size_t)MROWS * HID * 2;
  const size_t SZ_WQKV = (size_t)QKVN * HID * 2;
  const size_t SZ_WO = (size_t)HID * HID * 2;
  bf16* h_bf = (bf16*)(ws);
  bf16* wqkvT = (bf16*)(ws + SZ_H);
  bf16* woT = (bf16*)(ws + SZ_H + SZ_WQKV);
  bf16* qkv = (bf16*)(ws + SZ_H + SZ_WQKV + SZ_WO);
  bf16* attn = h_bf;
  bf16* vtbuf = wqkvT;

  const int GEMM_SMEM = 3 * 24576 * 2;   // 147456 B
  const int ATTN_SMEM = 40960 * 2;       // 81920 B
  auto* g1 = gemm256<bf16>;
  auto* g2 = gemm256<float>;
  hipFuncSetAttribute(reinterpret_cast<const void*>(g1),
                      hipFuncAttributeMaxDynamicSharedMemorySize, GEMM_SMEM);
  hipFuncSetAttribute(reinterpret_cast<const void*>(g2),
                      hipFuncAttributeMaxDynamicSharedMemorySize, GEMM_SMEM);
  hipFuncSetAttribute(reinterpret_cast<const void*>(attn_kernel),
                      hipFuncAttributeMaxDynamicSharedMemorySize, ATTN_SMEM);

  h2b_kernel<<<(MROWS * (long)HID) / (256 * 4), 256, 0, stream>>>(hidden, h_bf);
  dim3 t32(32, 8);
  wtrans_kernel<<<dim3(HID / 32, HID / 32), t32, 0, stream>>>(wq, wqkvT, HID, HID);
  wtrans_kernel<<<dim3(1024 / 32, HID / 32), t32, 0, stream>>>(wk, wqkvT + (long)4096 * HID, HID, 1024);
  wtrans_kernel<<<dim3(1024 / 32, HID / 32), t32, 0, stream>>>(wv, wqkvT + (long)5120 * HID, HID, 1024);
  wtrans_kernel<<<dim3(HID / 32, HID / 32), t32, 0, stream>>>(wo, woT, HID, HID);
  gemm256<bf16><<<dim3(QKVN / 128, MROWS / 256), 512, GEMM_SMEM, stream>>>(h_bf, wqkvT, qkv, MROWS, QKVN, HID);
  rope_kernel<<<(MROWS * 40 * 64) / 256, 256, 0, stream>>>(qkv, positions);
  vtrans_kernel<<<dim3(SEQ / 32, HD / 32, BATCH * NKVH), t32, 0, stream>>>(qkv, vtbuf);
  attn_kernel<<<dim3(8, NH, BATCH), 512, ATTN_SMEM, stream>>>(qkv, vtbuf, attn);
  gemm256<float><<<dim3(HID / 128, MROWS / 256), 512, GEMM_SMEM, stream>>>(attn, woT, out, MROWS, HID, HID);
}

// Round 8
// 553.255 us; speedup vs baseline: 2.3719x; 1.0030x over previous
//
#include <hip/hip_runtime.h>
#include <cstdint>

typedef __bf16 bf16;
typedef __attribute__((ext_vector_type(4))) __bf16 bf16x4;
typedef __attribute__((ext_vector_type(8))) __bf16 bf16x8;
typedef __attribute__((ext_vector_type(4))) float f32x4;

#define DEVI __device__ __forceinline__

#define BATCH 2
#define SEQ 2048
#define HID 4096
#define NH 32
#define NKVH 8
#define HD 128
#define QKVN 6144
#define MROWS 4096
#define ATT_SCALE 0.08838834764831845f
// scale folded with log2(e) so softmax uses exp2 directly
#define QSCALE (0.08838834764831845f * 1.4426950408889634f)

DEVI void gload_lds16(const bf16* g, bf16* l) {
  __builtin_amdgcn_global_load_lds(
      (__attribute__((address_space(1))) void*)(g),
      (__attribute__((address_space(3))) void*)(l), 16, 0, 0);
}

// ---------------- elementwise f32 -> bf16 ----------------
__global__ void h2b_kernel(const float* __restrict__ in, bf16* __restrict__ out) {
  long i = ((long)blockIdx.x * 256 + threadIdx.x) * 4;
  float4 v = *(const float4*)(in + i);
  bf16x4 o;
  o[0] = (bf16)v.x; o[1] = (bf16)v.y; o[2] = (bf16)v.z; o[3] = (bf16)v.w;
  *(bf16x4*)(out + i) = o;
}

// ---------------- transpose-convert weight: in (K,N) f32 -> out (N,K) bf16 ----------------
__global__ void wtrans_kernel(const float* __restrict__ in, bf16* __restrict__ out,
                              int K, int N) {
  __shared__ float t[32][33];
  int n0 = blockIdx.x * 32, k0 = blockIdx.y * 32;
  int tx = threadIdx.x, ty = threadIdx.y; // (32,8)
#pragma unroll
  for (int r = 0; r < 4; ++r) {
    int k = ty + r * 8;
    t[k][tx] = in[(long)(k0 + k) * N + n0 + tx];
  }
  __syncthreads();
#pragma unroll
  for (int r = 0; r < 4; ++r) {
    int n = ty + r * 8;
    out[(long)(n0 + n) * K + k0 + tx] = (bf16)t[tx][n];
  }
}

// ---------------- RoPE in-place on q,k columns of qkv ----------------
__global__ void rope_kernel(bf16* __restrict__ qkv, const int* __restrict__ pos) {
  long idx = (long)blockIdx.x * 256 + threadIdx.x;
  if (idx >= (long)MROWS * 40 * 64) return;
  int d = idx & 63;
  long t = idx >> 6;
  int hh = (int)(t % 40);
  int row = (int)(t / 40);
  int colb = hh < NH ? hh * HD : NH * HD + (hh - NH) * HD;
  float p = (float)pos[row];
  float inv_freq = exp2f((float)d * -0.2076205059304601f);
  float ang = p * inv_freq;
  float sn = sinf(ang), cs = cosf(ang);
  bf16* base = qkv + (long)row * QKVN + colb + d;
  float x1 = (float)base[0], x2 = (float)base[64];
  base[0] = (bf16)(x1 * cs - x2 * sn);
  base[64] = (bf16)(x2 * cs + x1 * sn);
}

// ---------------- transpose V: qkv v-cols -> vt (b,kvh,D,S) ----------------
__global__ void vtrans_kernel(const bf16* __restrict__ qkv, bf16* __restrict__ vt) {
  __shared__ bf16 t[32][33];
  int s0 = blockIdx.x * 32, d0 = blockIdx.y * 32, bk = blockIdx.z;
  int b = bk >> 3, kvh = bk & 7;
  int tx = threadIdx.x, ty = threadIdx.y; // (32,8)
#pragma unroll
  for (int r = 0; r < 4; ++r) {
    int s = ty + r * 8;
    t[s][tx] = qkv[(long)(b * SEQ + s0 + s) * QKVN + 5120 + kvh * HD + d0 + tx];
  }
  __syncthreads();
#pragma unroll
  for (int r = 0; r < 4; ++r) {
    int d = ty + r * 8;
    vt[((long)bk * HD + d0 + d) * SEQ + s0 + tx] = t[tx][d];
  }
}

// ---------------- 8-phase GEMM: C(M,N) = A(M,K) x BT(N,K)^T ----------------
// 256x256 tile, BK=64, 8 waves (2M x 4N), wave tile 128x64. LDS = 2buf x
// (A[256][64] + B[256][64]) = 128KB, 1 block/CU. 4 phases per K-tile by
// C-quadrant: (mh0,np0),(mh0,np1),(mh1,np1),(mh1,np0); ds_reads 12/4/8/0.
// STAGE->PHASE assignment (WAR-verified: each target's last LDS read is a
// barrier-separated earlier phase):
//   ph0: A-hi(t+1)  [opposite parity; last read tile t-1 ph2]
//   ph1: (none)     [A-lo region is read by wm=0 waves until ph2]
//   ph2: B-lo(t+2)  [last read ph1]
//   ph3: B-hi(t+2) + A-lo(t+2)  [last reads ph1 / ph2]
// Counted vmcnt(6) once per K-tile: entering tile t, outstanding =
// {B-lo(t+1),B-hi(t+1),A-lo(t+1)}; end-of-t drain covers those + A-hi(t+1),
// so tile t+1 is fully landed; 6 newest (t+2 halves) stay in flight.
// 16B-slot XOR swizzle: pre-swizzled GLOBAL source col, linear LDS dest, XOR on read.
template <typename OutT>
__global__ __launch_bounds__(512, 2)
void gemm8p(const bf16* __restrict__ A, const bf16* __restrict__ BT,
            OutT* __restrict__ C, int M, int N, int K) {
  extern __shared__ __align__(16) bf16 lds[];
  const int tid = threadIdx.x;
  const int lane = tid & 63, wave = tid >> 6;
  const int wm = wave >> 2, wn = wave & 3;   // 2M x 4N
  const int l16 = lane & 15, lhi = lane >> 4;
  // bijective XCD swizzle (nwg % 8 == 0 for our launches)
  const int nwg = gridDim.x * gridDim.y;
  const int bid = blockIdx.y * gridDim.x + blockIdx.x;
  const int cpx = nwg >> 3;
  const int swz = (bid & 7) * cpx + (bid >> 3);
  const int bx = swz % gridDim.x, by = swz / gridDim.x;
  const long bm0 = (long)by * 256, bn0 = (long)bx * 256;

  bf16* Alds = lds;              // [2 buf][2 half][128][64]
  bf16* Blds = lds + 32768;
  const int NT = K >> 6;

  f32x4 acc[8][4] = {};

  // stage one 128x64 half-tile (2 x gload_lds16 per thread)
  auto stageH = [&](const bf16* src, long row0, long k0, bf16* dst) {
#pragma unroll
    for (int j = 0; j < 2; ++j) {
      int r = j * 64 + (tid >> 3);
      int sc = (tid & 7) ^ (r & 7);
      gload_lds16(src + (row0 + r) * (long)K + k0 + sc * 8,
                  dst + j * 4096 + tid * 8);
    }
  };

  // prologue: tile0 all 4 halves, then tile1 {B-lo, B-hi, A-lo} (steady order)
  stageH(A, bm0, 0, Alds);
  stageH(A, bm0 + 128, 0, Alds + 8192);
  stageH(BT, bn0, 0, Blds);
  stageH(BT, bn0 + 128, 0, Blds + 8192);
  {
    long k1 = (NT > 1) ? 64 : 0;
    stageH(BT, bn0, k1, Blds + 16384);
    stageH(BT, bn0 + 128, k1, Blds + 24576);
    stageH(A, bm0, k1, Alds + 16384);
  }
  asm volatile("s_waitcnt vmcnt(6)" ::: "memory");
  __builtin_amdgcn_s_barrier();
  __builtin_amdgcn_sched_barrier(0);

  const int arow0 = wm * 128 + l16;
  const int brow0 = wn * 64 + l16;

  for (int t = 0; t < NT; ++t) {
    const bf16* Ab = Alds + (t & 1) * 16384;
    const bf16* Bb = Blds + (t & 1) * 16384;
    bf16* A1 = Alds + ((t + 1) & 1) * 16384;
    bf16* A2 = Alds + (t & 1) * 16384;       // (t+2) parity == t parity
    bf16* B2 = Blds + (t & 1) * 16384;
    const long k1 = (long)((t + 1 < NT) ? t + 1 : NT - 1) << 6;
    const long k2 = (long)((t + 2 < NT) ? t + 2 : NT - 1) << 6;

    bf16x8 a0[4][2], a1r[4][2], b0[2][2], b1[2][2];
    // ---- phase 0: q(mh0,np0). reads A-h0 (8) + B-p0 (4); stage A-hi(t+1)
#pragma unroll
    for (int i = 0; i < 4; ++i) {
      int mr = arow0 + i * 16;
#pragma unroll
      for (int kk = 0; kk < 2; ++kk)
        a0[i][kk] = *(const bf16x8*)(Ab + mr * 64 + (((kk * 4 + lhi) ^ (mr & 7))) * 8);
    }
#pragma unroll
    for (int n = 0; n < 2; ++n) {
      int br = brow0 + n * 16;
#pragma unroll
      for (int kk = 0; kk < 2; ++kk)
        b0[n][kk] = *(const bf16x8*)(Bb + br * 64 + (((kk * 4 + lhi) ^ (br & 7))) * 8);
    }
    stageH(A, bm0 + 128, k1, A1 + 8192);
    __builtin_amdgcn_sched_barrier(0);
    __builtin_amdgcn_s_barrier();
    __builtin_amdgcn_sched_barrier(0);
    __builtin_amdgcn_s_setprio(1);
#pragma unroll
    for (int i = 0; i < 4; ++i)
#pragma unroll
      for (int n = 0; n < 2; ++n)
#pragma unroll
        for (int kk = 0; kk < 2; ++kk)
          acc[i][n] = __builtin_amdgcn_mfma_f32_16x16x32_bf16(a0[i][kk], b0[n][kk], acc[i][n], 0, 0, 0);
    __builtin_amdgcn_s_setprio(0);
    __builtin_amdgcn_sched_barrier(0);
    __builtin_amdgcn_s_barrier();
    // ---- phase 1: q(mh0,np1). reads B-p1 (4); NO stage (A-lo still live)
#pragma unroll
    for (int n = 0; n < 2; ++n) {
      int br = brow0 + (n + 2) * 16;
#pragma unroll
      for (int kk = 0; kk < 2; ++kk)
        b1[n][kk] = *(const bf16x8*)(Bb + br * 64 + (((kk * 4 + lhi) ^ (br & 7))) * 8);
    }
    __builtin_amdgcn_sched_barrier(0);
    __builtin_amdgcn_s_barrier();
    __builtin_amdgcn_sched_barrier(0);
    __builtin_amdgcn_s_setprio(1);
#pragma unroll
    for (int i = 0; i < 4; ++i)
#pragma unroll
      for (int n = 0; n < 2; ++n)
#pragma unroll
        for (int kk = 0; kk < 2; ++kk)
          acc[i][n + 2] = __builtin_amdgcn_mfma_f32_16x16x32_bf16(a0[i][kk], b1[n][kk], acc[i][n + 2], 0, 0, 0);
    __builtin_amdgcn_s_setprio(0);
    __builtin_amdgcn_sched_barrier(0);
    __builtin_amdgcn_s_barrier();
    // ---- phase 2: q(mh1,np1). reads A-h1 (8); stage B-lo(t+2)
#pragma unroll
    for (int i = 0; i < 4; ++i) {
      int mr = arow0 + 64 + i * 16;
#pragma unroll
      for (int kk = 0; kk < 2; ++kk)
        a1r[i][kk] = *(const bf16x8*)(Ab + mr * 64 + (((kk * 4 + lhi) ^ (mr & 7))) * 8);
    }
    stageH(BT, bn0, k2, B2);
    __builtin_amdgcn_sched_barrier(0);
    __builtin_amdgcn_s_barrier();
    __builtin_amdgcn_sched_barrier(0);
    __builtin_amdgcn_s_setprio(1);
#pragma unroll
    for (int i = 0; i < 4; ++i)
#pragma unroll
      for (int n = 0; n < 2; ++n)
#pragma unroll
        for (int kk = 0; kk < 2; ++kk)
          acc[4 + i][n + 2] = __builtin_amdgcn_mfma_f32_16x16x32_bf16(a1r[i][kk], b1[n][kk], acc[4 + i][n + 2], 0, 0, 0);
    __builtin_amdgcn_s_setprio(0);
    __builtin_amdgcn_sched_barrier(0);
    __builtin_amdgcn_s_barrier();
    // ---- phase 3: q(mh1,np0). no reads; stage B-hi(t+2) + A-lo(t+2)
    stageH(BT, bn0 + 128, k2, B2 + 8192);
    stageH(A, bm0, k2, A2);
    __builtin_amdgcn_sched_barrier(0);
    __builtin_amdgcn_s_barrier();
    __builtin_amdgcn_sched_barrier(0);
    __builtin_amdgcn_s_setprio(1);
#pragma unroll
    for (int i = 0; i < 4; ++i)
#pragma unroll
      for (int n = 0; n < 2; ++n)
#pragma unroll
        for (int kk = 0; kk < 2; ++kk)
          acc[4 + i][n] = __builtin_amdgcn_mfma_f32_16x16x32_bf16(a1r[i][kk], b0[n][kk], acc[4 + i][n], 0, 0, 0);
    __builtin_amdgcn_s_setprio(0);
    __builtin_amdgcn_sched_barrier(0);
    asm volatile("s_waitcnt vmcnt(6)" ::: "memory");  // tile t+1 fully landed
    __builtin_amdgcn_s_barrier();
    __builtin_amdgcn_sched_barrier(0);
  }
  asm volatile("s_waitcnt vmcnt(0)" ::: "memory");  // drain clamped tail loads
  // epilogue: C rows bm0 + wm*128 + mi*16 + lhi*4 + r, cols bn0 + wn*64 + n*16 + l16
#pragma unroll
  for (int mi = 0; mi < 8; ++mi)
#pragma unroll
    for (int r = 0; r < 4; ++r) {
      long grow = bm0 + wm * 128 + mi * 16 + lhi * 4 + r;
#pragma unroll
      for (int n = 0; n < 4; ++n) {
        long gcol = bn0 + wn * 64 + n * 16 + l16;
        C[grow * N + gcol] = (OutT)acc[mi][n][r];
      }
    }
}

// ---------------- flash attention: work-balanced paired chunks ----------------
// 512 threads = 8 waves x 16 q-rows = 128-row chunk. Each block processes chunk
// pi AND chunk 15-pi sequentially: total K/V steps = (2pi+2)+(32-2pi) = 34 for
// EVERY block. Grid = 8x32x2 = 512 equal blocks = exactly 2/CU: one balanced
// round, no tail. Swapped-QK^T lane-local softmax, defer-rescale (T13), K/V
// double-buffered via global_load_lds with XOR swizzle.
__global__ __launch_bounds__(512, 4)
void attn_kernel(const bf16* __restrict__ qkv, const bf16* __restrict__ vt,
                 bf16* __restrict__ out) {
  extern __shared__ __align__(16) bf16 smem[];
  // layout (elems): K0 0, K1 8192, V0 16384, V1 24576, P 32768 (8 x 1024)
  const int pi = blockIdx.x, h = blockIdx.y, b = blockIdx.z;
  const int kvh = h >> 2;
  const int tid = threadIdx.x, lane = tid & 63, wave = tid >> 6;
  const int l16 = lane & 15, lhi = lane >> 4;
  const int kloc = lhi * 4;
  bf16* Pw = smem + 32768 + wave * 1024;

  const bf16* kpan = qkv + (long)(b * SEQ) * QKVN + 4096 + kvh * HD;
  const bf16* vpan = vt + (long)(b * NKVH + kvh) * HD * SEQ;

  auto stageKV = [&](int buf, int step) {
    const int kv0 = step * 64;
    bf16* kd = smem + buf * 8192;
    bf16* vd = smem + 16384 + buf * 8192;
#pragma unroll
    for (int i = 0; i < 2; ++i) {
      int kr = wave * 8 + i * 4 + lhi;
      gload_lds16(kpan + (long)(kv0 + kr) * QKVN + (l16 ^ (kr & 7)) * 8,
                  kd + (wave * 8 + i * 4) * 128);
      int vr = wave * 16 + i * 8 + (lane >> 3);
      gload_lds16(vpan + (long)vr * SEQ + kv0 + ((lane & 7) ^ (vr & 7)) * 8,
                  vd + (wave * 16 + i * 8) * 64);
    }
  };

  auto process_chunk = [&](int q0, int nsteps) {
    bf16x8 qf[4];
    const bf16* qb = qkv + (long)(b * SEQ + q0 + wave * 16 + l16) * QKVN + h * HD + lhi * 8;
#pragma unroll
    for (int di = 0; di < 4; ++di) {
      bf16x8 raw = *(const bf16x8*)(qb + di * 32);
      bf16x8 sc;
#pragma unroll
      for (int j = 0; j < 8; ++j) sc[j] = (bf16)((float)raw[j] * QSCALE);
      qf[di] = sc;
    }
    f32x4 oacc[8] = {};
    float m_run = -1e30f, l_run = 0.f;
    const int qg = q0 + wave * 16 + l16;

    stageKV(0, 0);
    __syncthreads();

    for (int step = 0; step < nsteps; ++step) {
      const int kv0 = step * 64;
      const int cur = step & 1;
      if (step + 1 < nsteps) stageKV(cur ^ 1, step + 1);
      const bf16* Kc = smem + cur * 8192;
      const bf16* Vc = smem + 16384 + cur * 8192;

      f32x4 s[4];
      __builtin_amdgcn_s_setprio(1);
#pragma unroll
      for (int c = 0; c < 4; ++c) {
        s[c] = (f32x4){0.f, 0.f, 0.f, 0.f};
        int kr = c * 16 + l16;
#pragma unroll
        for (int di = 0; di < 4; ++di) {
          bf16x8 kf = *(const bf16x8*)(Kc + kr * 128 + (((di * 4 + lhi) ^ (kr & 7))) * 8);
          s[c] = __builtin_amdgcn_mfma_f32_16x16x32_bf16(kf, qf[di], s[c], 0, 0, 0);
        }
      }
      __builtin_amdgcn_s_setprio(0);
#pragma unroll
      for (int c = 0; c < 4; ++c)
#pragma unroll
        for (int r = 0; r < 4; ++r) {
          int kcol = kv0 + c * 16 + kloc + r;
          if (kcol > qg) s[c][r] = -1e30f;
        }
      float mloc = s[0][0];
#pragma unroll
      for (int c = 0; c < 4; ++c)
#pragma unroll
        for (int r = 0; r < 4; ++r) mloc = fmaxf(mloc, s[c][r]);
      mloc = fmaxf(mloc, __shfl_xor(mloc, 16, 64));
      mloc = fmaxf(mloc, __shfl_xor(mloc, 32, 64));
      bool skip = __all(mloc - m_run <= 8.0f);
      float alpha = 1.f;
      if (!skip) {
        float mn = fmaxf(m_run, mloc);
        alpha = exp2f(m_run - mn);
        m_run = mn;
      }
      float sm = 0.f;
      bf16x4 pb[4];
#pragma unroll
      for (int c = 0; c < 4; ++c)
#pragma unroll
        for (int r = 0; r < 4; ++r) {
          float p = exp2f(s[c][r] - m_run);
          sm += p;
          pb[c][r] = (bf16)p;
        }
      sm += __shfl_xor(sm, 16, 64);
      sm += __shfl_xor(sm, 32, 64);
      l_run = l_run * alpha + sm;
#pragma unroll
      for (int c = 0; c < 4; ++c) {
        int sl = (c * 2 + (lhi >> 1)) ^ (l16 & 7);
        *(bf16x4*)(Pw + l16 * 64 + sl * 8 + (lhi & 1) * 4) = pb[c];
      }
      if (!skip) {
        float a_o[4];
#pragma unroll
        for (int r = 0; r < 4; ++r) a_o[r] = __shfl(alpha, kloc + r, 64);
#pragma unroll
        for (int dj = 0; dj < 8; ++dj)
#pragma unroll
          for (int r = 0; r < 4; ++r) oacc[dj][r] *= a_o[r];
      }
      __builtin_amdgcn_s_setprio(1);
#pragma unroll
      for (int kh = 0; kh < 2; ++kh) {
        bf16x8 pf = *(const bf16x8*)(Pw + l16 * 64 + (((kh * 4 + lhi) ^ (l16 & 7))) * 8);
#pragma unroll
        for (int dj = 0; dj < 8; ++dj) {
          int vr = dj * 16 + l16;
          bf16x8 vf = *(const bf16x8*)(Vc + vr * 64 + (((kh * 4 + lhi) ^ (vr & 7))) * 8);
          oacc[dj] = __builtin_amdgcn_mfma_f32_16x16x32_bf16(pf, vf, oacc[dj], 0, 0, 0);
        }
      }
      __builtin_amdgcn_s_setprio(0);
      __syncthreads();
    }
    float linv[4];
#pragma unroll
    for (int r = 0; r < 4; ++r) linv[r] = 1.f / __shfl(l_run, kloc + r, 64);
#pragma unroll
    for (int r = 0; r < 4; ++r) {
      long orow = (long)(b * SEQ + q0 + wave * 16 + lhi * 4 + r);
#pragma unroll
      for (int dj = 0; dj < 8; ++dj)
        out[orow * (NH * HD) + h * HD + dj * 16 + l16] = (bf16)(oacc[dj][r] * linv[r]);
    }
  };

  process_chunk(pi * 128, 2 * pi + 2);          // light chunk
  process_chunk((15 - pi) * 128, 32 - 2 * pi);  // heavy chunk: total 34 steps/block
}

extern "C" void kernel_launch(void* const* d_in, const int* in_sizes, int n_in,
                              void* d_out, int out_size, void* d_ws, size_t ws_size,
                              hipStream_t stream) {
  const int* positions = (const int*)d_in[0];
  const float* hidden = (const float*)d_in[1];
  const float* wq = (const float*)d_in[2];
  const float* wk = (const float*)d_in[3];
  const float* wv = (const float*)d_in[4];
  const float* wo = (const float*)d_in[5];
  float* out = (float*)d_out;
  char* ws = (char*)d_ws;

  const size_t SZ_H = (size_t)MROWS * HID * 2;
  const size_t SZ_WQKV = (size_t)QKVN * HID * 2;
  const size_t SZ_WO = (size_t)HID * HID * 2;
  bf16* h_bf = (bf16*)(ws);
  bf16* wqkvT = (bf16*)(ws + SZ_H);
  bf16* woT = (bf16*)(ws + SZ_H + SZ_WQKV);
  bf16* qkv = (bf16*)(ws + SZ_H + SZ_WQKV + SZ_WO);
  bf16* attn = h_bf;
  bf16* vtbuf = wqkvT;

  const int GEMM_SMEM = 131072;        // 2buf x (A+B) x 256x64 x 2B
  const int ATTN_SMEM = 40960 * 2;     // 81920 B
  auto* g1 = gemm8p<bf16>;
  auto* g2 = gemm8p<float>;
  hipFuncSetAttribute(reinterpret_cast<const void*>(g1),
                      hipFuncAttributeMaxDynamicSharedMemorySize, GEMM_SMEM);
  hipFuncSetAttribute(reinterpret_cast<const void*>(g2),
                      hipFuncAttributeMaxDynamicSharedMemorySize, GEMM_SMEM);
  hipFuncSetAttribute(reinterpret_cast<const void*>(attn_kernel),
                      hipFuncAttributeMaxDynamicSharedMemorySize, ATTN_SMEM);

  h2b_kernel<<<(MROWS * (long)HID) / (256 * 4), 256, 0, stream>>>(hidden, h_bf);
  dim3 t32(32, 8);
  wtrans_kernel<<<dim3(HID / 32, HID / 32), t32, 0, stream>>>(wq, wqkvT, HID, HID);
  wtrans_kernel<<<dim3(1024 / 32, HID / 32), t32, 0, stream>>>(wk, wqkvT + (long)4096 * HID, HID, 1024);
  wtrans_kernel<<<dim3(1024 / 32, HID / 32), t32, 0, stream>>>(wv, wqkvT + (long)5120 * HID, HID, 1024);
  wtrans_kernel<<<dim3(HID / 32, HID / 32), t32, 0, stream>>>(wo, woT, HID, HID);
  gemm8p<bf16><<<dim3(QKVN / 256, MROWS / 256), 512, GEMM_SMEM, stream>>>(h_bf, wqkvT, qkv, MROWS, QKVN, HID);
  rope_kernel<<<(MROWS * 40 * 64) / 256, 256, 0, stream>>>(qkv, positions);
  vtrans_kernel<<<dim3(SEQ / 32, HD / 32, BATCH * NKVH), t32, 0, stream>>>(qkv, vtbuf);
  attn_kernel<<<dim3(8, NH, BATCH), 512, ATTN_SMEM, stream>>>(qkv, vtbuf, attn);
  gemm8p<float><<<dim3(HID / 256, MROWS / 256), 512, GEMM_SMEM, stream>>>(attn, woT, out, MROWS, HID, HID);
}